// Round 9
// baseline (3764.493 us; speedup 1.0000x reference)
//
#include <hip/hip_runtime.h>
#include <cstdint>
#include <cmath>

// Problem constants (fixed by reference):
//   B=64 examples, D=128 dim, NP=512 nodes/tokens per example, 100 Jacobi Sinkhorn iters.
#define NB_EX 64
#define DIMD 128
#define NP 512
constexpr float MARG = 1.0f / 512.0f;   // a = b = 1/n

// ---------- helpers ----------
__device__ __forceinline__ float bf2f_lo(unsigned w) { return __uint_as_float(w << 16); }
__device__ __forceinline__ float bf2f_hi(unsigned w) { return __uint_as_float(w & 0xFFFF0000u); }
__device__ __forceinline__ unsigned short f2bf(float f) {
    unsigned u = __float_as_uint(f);
    u += 0x7FFFu + ((u >> 16) & 1u);      // RTNE
    return (unsigned short)(u >> 16);
}
__device__ __forceinline__ float wred64(float v) {
#pragma unroll
    for (int m = 1; m < 64; m <<= 1) v += __shfl_xor(v, m, 64);
    return v;
}

// Per-block dtype self-detection (bf16-pair low halfword exponent clusters in [110,130];
// fp32 low mantissa bits hit ~8%). 256-thread blocks only. Costs one syncthreads.
__device__ __forceinline__ int self_detect(const unsigned* probe, int t) {
    __shared__ int sd_cnt[4];
    unsigned w = probe[t];
    unsigned e = (w >> 7) & 0xFFu;
    unsigned long long m = __ballot(e >= 110u && e <= 130u);
    if ((t & 63) == 0) sd_cnt[t >> 6] = __popcll(m);
    __syncthreads();
    int c = sd_cnt[0] + sd_cnt[1] + sd_cnt[2] + sd_cnt[3];
    __syncthreads();
    return c >= 128;
}

// ---------- workspace layout (bytes) ----------
#define O_SIMG   0               // 64*64 f32 (16384)
#define O_RNAN   16384           // 32768 f32 (131072)
#define O_RNBN   147456          // 32768 f32 (131072)
#define O_COLP   278528          // 64ex x 512 tagged u32 (128 KB; region reserves 4 MB)
#define O_P0     4472832         // 64*512*512 bf16 (33554432) -> total ~38 MB

// ---------- fused inverse L2 norms for struct_nodes + seq_tokens (65536 rows) ----------
__global__ void k_rnormAB(const void* anr, const void* bnr, float* rnan, float* rnbn) {
    int t = threadIdx.x;
    int flag = self_detect((const unsigned*)anr, t);
    int gr  = blockIdx.x * 4 + (t >> 6);      // global row 0..65535
    int lane = t & 63;
    const void* in = (gr < 32768) ? anr : bnr;
    float* rn      = (gr < 32768) ? rnan : rnbn;
    int row = gr & 32767;
    float f0, f1;
    if (flag) {
        unsigned w = ((const unsigned*)in)[row * 64 + lane];
        f0 = bf2f_lo(w); f1 = bf2f_hi(w);
    } else {
        float2 v = ((const float2*)in)[row * 64 + lane];
        f0 = v.x; f1 = v.y;
    }
    float ss = wred64(f0 * f0 + f1 * f1);
    if (lane == 0) rn[row] = 1.0f / fmaxf(sqrtf(ss), 1e-12f);
}

// ---------- global sim logits (self-detecting, self-normalizing) ----------
__global__ void k_simg(const void* sgr, const void* qgr, float* simg) {
    __shared__ float rls[128];                // [0..63]=1/||s_i||, [64..127]=1/||q_j||
    int t = threadIdx.x;
    int flag = self_detect((const unsigned*)sgr, t);
    int w = t >> 6, lane = t & 63;
    for (int rr = 0; rr < 32; rr++) {         // each wave: 32 of 128 rows
        int ri = w * 32 + rr;
        const void* base = (ri < 64) ? sgr : qgr;
        int row = ri & 63;
        float f0, f1;
        if (flag) {
            unsigned wd = ((const unsigned*)base)[row * 64 + lane];
            f0 = bf2f_lo(wd); f1 = bf2f_hi(wd);
        } else {
            float2 v = ((const float2*)base)[row * 64 + lane];
            f0 = v.x; f1 = v.y;
        }
        float ss = wred64(f0 * f0 + f1 * f1);
        if (lane == 0) rls[ri] = 1.0f / fmaxf(sqrtf(ss), 1e-12f);
    }
    __syncthreads();
    int g = blockIdx.x * 256 + t;             // 4096 = 64*64
    int i = g >> 6, j = g & 63;
    float dot = 0.f;
    if (flag) {
        const unsigned* a = (const unsigned*)sgr + i * 64;
        const unsigned* b = (const unsigned*)qgr + j * 64;
        for (int k = 0; k < 64; k++) {
            unsigned wa = a[k], wb = b[k];
            dot += bf2f_lo(wa) * bf2f_lo(wb);
            dot += bf2f_hi(wa) * bf2f_hi(wb);
        }
    } else {
        const float4* a = (const float4*)sgr + i * 32;
        const float4* b = (const float4*)qgr + j * 32;
        for (int k = 0; k < 32; k++) {
            float4 x = a[k], y = b[k];
            dot += x.x * y.x + x.y * y.y + x.z * y.z + x.w * y.w;
        }
    }
    simg[g] = dot * rls[i] * rls[64 + j] * 10.0f;   // /TEMP = *10
}

// ---------- global NT-Xent; initializes all 3 outputs (stores, not adds) ----------
__global__ void k_gloss(const float* __restrict__ simg, float* outf) {
    __shared__ float red[64];
    int i = threadIdx.x;
    if (i < 64) {
        float m = -1e30f;
        for (int j = 0; j < 64; j++) m = fmaxf(m, simg[i * 64 + j]);
        float se = 0.f;
        for (int j = 0; j < 64; j++) se += expf(simg[i * 64 + j] - m);
        float rl = simg[i * 64 + i] - (m + logf(se));
        float m2 = -1e30f;
        for (int j = 0; j < 64; j++) m2 = fmaxf(m2, simg[j * 64 + i]);
        float se2 = 0.f;
        for (int j = 0; j < 64; j++) se2 += expf(simg[j * 64 + i] - m2);
        float cl = simg[i * 64 + i] - (m2 + logf(se2));
        red[i] = rl + cl;
    }
    __syncthreads();
    if (i == 0) {
        float s = 0.f;
        for (int k = 0; k < 64; k++) s += red[k];
        float g = -s / 128.0f;
        outf[0] = g;          // global loss
        outf[1] = 0.0f;       // local loss accumulated by k_persist
        outf[2] = g;          // total = g + local (added by k_persist)
    }
}

// ---------- build P0 = exp(10*sim) bf16, per-example 512x512, 128x128 tiles ----------
__global__ void k_build(const void* anr, const void* bnr, const float* rnan, const float* rnbn,
                        unsigned short* p0) {
    int t  = threadIdx.x;
    int flag = self_detect((const unsigned*)anr, t);
    int b   = blockIdx.y;
    int r0t = (blockIdx.x >> 2) * 128;
    int c0t = (blockIdx.x & 3) * 128;
    __shared__ float As[128][33];
    __shared__ float Bs[128][33];
    int tr = t >> 4, tc = t & 15;
    float acc[8][8];
#pragma unroll
    for (int i = 0; i < 8; i++)
#pragma unroll
        for (int j = 0; j < 8; j++) acc[i][j] = 0.f;

    for (int kc = 0; kc < 4; kc++) {            // K chunks of 32
        for (int ii = 0; ii < 4; ii++) {
            int idx = t + 256 * ii;             // 0..1023 -> 128 rows x 8 float4
            int r = idx >> 3, c4 = idx & 7;
            {   // A chunk (struct_nodes)
                int grow = b * NP + r0t + r;
                float sc = rnan[grow];
                float f0, f1, f2, f3;
                if (flag) {
                    const unsigned* src = (const unsigned*)anr + ((grow * DIMD + kc * 32 + c4 * 4) >> 1);
                    unsigned w0 = src[0], w1 = src[1];
                    f0 = bf2f_lo(w0); f1 = bf2f_hi(w0); f2 = bf2f_lo(w1); f3 = bf2f_hi(w1);
                } else {
                    float4 v = *((const float4*)((const float*)anr + grow * DIMD + kc * 32 + c4 * 4));
                    f0 = v.x; f1 = v.y; f2 = v.z; f3 = v.w;
                }
                As[r][c4 * 4 + 0] = f0 * sc; As[r][c4 * 4 + 1] = f1 * sc;
                As[r][c4 * 4 + 2] = f2 * sc; As[r][c4 * 4 + 3] = f3 * sc;
            }
            {   // B chunk (seq_tokens)
                int grow = b * NP + c0t + r;
                float sc = rnbn[grow];
                float f0, f1, f2, f3;
                if (flag) {
                    const unsigned* src = (const unsigned*)bnr + ((grow * DIMD + kc * 32 + c4 * 4) >> 1);
                    unsigned w0 = src[0], w1 = src[1];
                    f0 = bf2f_lo(w0); f1 = bf2f_hi(w0); f2 = bf2f_lo(w1); f3 = bf2f_hi(w1);
                } else {
                    float4 v = *((const float4*)((const float*)bnr + grow * DIMD + kc * 32 + c4 * 4));
                    f0 = v.x; f1 = v.y; f2 = v.z; f3 = v.w;
                }
                Bs[r][c4 * 4 + 0] = f0 * sc; Bs[r][c4 * 4 + 1] = f1 * sc;
                Bs[r][c4 * 4 + 2] = f2 * sc; Bs[r][c4 * 4 + 3] = f3 * sc;
            }
        }
        __syncthreads();
        for (int kk = 0; kk < 32; kk++) {
            float av[8], bv[8];
#pragma unroll
            for (int i = 0; i < 8; i++) av[i] = As[tr * 8 + i][kk];
#pragma unroll
            for (int j = 0; j < 8; j++) bv[j] = Bs[tc * 8 + j][kk];
#pragma unroll
            for (int i = 0; i < 8; i++)
#pragma unroll
                for (int j = 0; j < 8; j++) acc[i][j] += av[i] * bv[j];
        }
        __syncthreads();
    }
#pragma unroll
    for (int i = 0; i < 8; i++) {
        int grow = b * NP + r0t + tr * 8 + i;
        unsigned short h[8];
#pragma unroll
        for (int j = 0; j < 8; j++) h[j] = f2bf(expf(acc[i][j] * 10.0f));   // exp(sim/REG)
        uint4 pk;
        pk.x = (unsigned)h[0] | ((unsigned)h[1] << 16);
        pk.y = (unsigned)h[2] | ((unsigned)h[3] << 16);
        pk.z = (unsigned)h[4] | ((unsigned)h[5] << 16);
        pk.w = (unsigned)h[6] | ((unsigned)h[7] << 16);
        *((uint4*)(p0 + ((size_t)grow * NP + c0t + tc * 8))) = pk;
    }
}

// ---------- exchange-free persistent Sinkhorn ----------
// R5/R6/R8 evidence: ANY per-iteration cross-block exchange costs ~3-4 us of fabric
// latency that pipelining cannot hide (Jacobi chain is sequential). Fix: split the
// recurrence into its two DISJOINT dependency chains:
//   u_100 depends only on {u_even, v_odd}:  50x [v'=b/(P0^T u); u=a/(P0 v')]
//   v_100 depends only on {u_odd, v_even}:  50x [u'=a/(P0 v); v=b/(P0^T u')]
// Together = exactly the reference's 200 matvecs (zero redundancy). One block per
// (example, chain): 128 blocks x 1024 thr; the block holds the WHOLE 512x512 P0 in
// registers (32 uint4/thread = 128 VGPR; ~170 total, well under the 512 budget at
// launch_bounds(1024,1) -> no spill, the R7 failure mode). All 100 iterations are
// LDS-internal (2 syncs/double-step). The ONLY cross-block exchange: v-chain block
// publishes tagged-bf16 v_100 once; u-chain block polls once and contracts.
// Tag=1 never collides with 0xAA-poisoned stale ws (0xAAAA).
// Layout: wave w owns rows w*32..+32; lane owns cols lane*8..+8 (uint4-packed).
// u lives as one register per lane (lane r holds u[w*32+r]); broadcast via __shfl.
__global__ __launch_bounds__(1024, 1) void k_persist(const unsigned short* __restrict__ p0,
                                                     unsigned* __restrict__ colp,
                                                     float* __restrict__ outf) {
    int b     = blockIdx.x >> 1;     // example
    int chain = blockIdx.x & 1;      // 0: u-chain, 1: v-chain
    int t = threadIdx.x, w = t >> 6, lane = t & 63;

    __shared__ float colred[16][512];
    __shared__ float v_s[512];
    __shared__ float bs[16];

    // load this block's whole-example P0 slice into registers (rows w*32..+32, cols lane*8..+8)
    uint4 pv[32];
#pragma unroll
    for (int r = 0; r < 32; ++r) {
        int row = (w << 5) + r;
        pv[r] = ((const uint4*)(p0 + (((size_t)(b << 9) + row) << 9)))[lane];
    }
    float u_mine = MARG;             // lane r (<32) holds u[w*32+r]; init u_0 = a
    if (t < 512) v_s[t] = MARG;      // v_0 = b
    __syncthreads();

    // ---- col half-step: colred <- partials of P0^T u ; then v_s = b/(col sums) ----
    auto col_step = [&]() {
        float ca[8];
#pragma unroll
        for (int k = 0; k < 8; ++k) ca[k] = 0.f;
#pragma unroll
        for (int r = 0; r < 32; ++r) {
            float u_r = __shfl(u_mine, r, 64);
            uint4 p = pv[r];
            ca[0] += bf2f_lo(p.x) * u_r; ca[1] += bf2f_hi(p.x) * u_r;
            ca[2] += bf2f_lo(p.y) * u_r; ca[3] += bf2f_hi(p.y) * u_r;
            ca[4] += bf2f_lo(p.z) * u_r; ca[5] += bf2f_hi(p.z) * u_r;
            ca[6] += bf2f_lo(p.w) * u_r; ca[7] += bf2f_hi(p.w) * u_r;
        }
#pragma unroll
        for (int k = 0; k < 8; ++k) colred[w][lane * 8 + k] = ca[k];
        __syncthreads();
        if (t < 512) {
            float raw = 0.f;
#pragma unroll
            for (int p = 0; p < 16; ++p) raw += colred[p][t];
            float q = MARG * __builtin_amdgcn_rcpf(raw);
            if (!isfinite(q)) q = MARG;           // nan_to_num(-> 1/m)
            v_s[t] = q;
        }
        __syncthreads();
    };

    // ---- row half-step: u = a/(P0 v) kept in per-lane register ----
    auto row_step = [&]() {
        float vr[8];
#pragma unroll
        for (int k = 0; k < 8; ++k) vr[k] = v_s[lane * 8 + k];
#pragma unroll
        for (int r = 0; r < 32; ++r) {
            uint4 p = pv[r];
            float rd = bf2f_lo(p.x) * vr[0] + bf2f_hi(p.x) * vr[1]
                     + bf2f_lo(p.y) * vr[2] + bf2f_hi(p.y) * vr[3]
                     + bf2f_lo(p.z) * vr[4] + bf2f_hi(p.z) * vr[5]
                     + bf2f_lo(p.w) * vr[6] + bf2f_hi(p.w) * vr[7];
            rd = wred64(rd);                      // all lanes hold the row sum
            float q = MARG * __builtin_amdgcn_rcpf(rd);
            if (!isfinite(q)) q = MARG;           // nan_to_num(-> 1/n)
            u_mine = (lane == r) ? q : u_mine;
        }
    };

    if (chain == 0) {
        // u-chain: 50 x [col ; row] -> u_mine = u_100
#pragma unroll 1
        for (int s = 0; s < 50; ++s) { col_step(); row_step(); }
        // fetch v_100 (published once by the sibling block)
        if (t < 512) {
            const unsigned* src = &colp[(b << 9) + t];
            unsigned g;
            for (;;) {
                g = __hip_atomic_load(src, __ATOMIC_RELAXED, __HIP_MEMORY_SCOPE_AGENT);
                if ((g & 0xFFFFu) == 1u) break;
                __builtin_amdgcn_s_sleep(2);
            }
            v_s[t] = __uint_as_float(g & 0xFFFF0000u);
        }
        __syncthreads();
        // final contraction: sum u * p * v * (-0.1 * ln p)   [C = -log(P0)/10]
        float vr[8];
#pragma unroll
        for (int k = 0; k < 8; ++k) vr[k] = v_s[lane * 8 + k];
        float acc = 0.f;
#pragma unroll
        for (int r = 0; r < 32; ++r) {
            float u_r = __shfl(u_mine, r, 64);
            uint4 p = pv[r];
            float f[8];
            f[0] = bf2f_lo(p.x); f[1] = bf2f_hi(p.x);
            f[2] = bf2f_lo(p.y); f[3] = bf2f_hi(p.y);
            f[4] = bf2f_lo(p.z); f[5] = bf2f_hi(p.z);
            f[6] = bf2f_lo(p.w); f[7] = bf2f_hi(p.w);
#pragma unroll
            for (int k = 0; k < 8; ++k)
                acc += u_r * f[k] * vr[k] * (-0.1f) * __logf(f[k]);
        }
        acc = wred64(acc);
        if (lane == 0) bs[w] = acc;
        __syncthreads();
        if (t == 0) {
            float c = 0.f;
#pragma unroll
            for (int k = 0; k < 16; ++k) c += bs[k];
            c *= (1.0f / 64.0f);                  // /B
            atomicAdd(&outf[1], c);
            atomicAdd(&outf[2], c);
        }
    } else {
        // v-chain: 50 x [row ; col] -> v_s = v_100; publish once, tagged
#pragma unroll 1
        for (int s = 0; s < 50; ++s) { row_step(); col_step(); }
        if (t < 512) {
            unsigned pk = ((unsigned)f2bf(v_s[t]) << 16) | 1u;
            __hip_atomic_store(&colp[(b << 9) + t], pk, __ATOMIC_RELAXED,
                               __HIP_MEMORY_SCOPE_AGENT);
        }
    }
}

extern "C" void kernel_launch(void* const* d_in, const int* in_sizes, int n_in,
                              void* d_out, int out_size, void* d_ws, size_t ws_size,
                              hipStream_t stream) {
    const void* sg = d_in[0];
    const void* qg = d_in[1];
    const void* an = d_in[2];
    const void* bn = d_in[3];
    char* ws = (char*)d_ws;
    float* outf = (float*)d_out;                     // output dtype: float32 x3

    float* simg     = (float*)(ws + O_SIMG);
    float* rnan     = (float*)(ws + O_RNAN);
    float* rnbn     = (float*)(ws + O_RNBN);
    unsigned* colp  = (unsigned*)(ws + O_COLP);      // v_100 publication (tagged)
    unsigned short* p0 = (unsigned short*)(ws + O_P0);

    k_rnormAB<<<16384, 256, 0, stream>>>(an, bn, rnan, rnbn);
    k_simg<<<16, 256, 0, stream>>>(sg, qg, simg);
    k_gloss<<<1, 256, 0, stream>>>(simg, outf);
    k_build<<<dim3(16, 64), 256, 0, stream>>>(an, bn, rnan, rnbn, p0);
    k_persist<<<128, 1024, 0, stream>>>(p0, colp, outf);
}

// Round 10
// 1529.859 us; speedup vs baseline: 2.4607x; 2.4607x over previous
//
#include <hip/hip_runtime.h>
#include <cstdint>
#include <cmath>

// Problem constants (fixed by reference):
//   B=64 examples, D=128 dim, NP=512 nodes/tokens per example, 100 Jacobi Sinkhorn iters.
#define NB_EX 64
#define DIMD 128
#define NP 512
constexpr float MARG = 1.0f / 512.0f;   // a = b = 1/n

// ---------- helpers ----------
__device__ __forceinline__ float bf2f_lo(unsigned w) { return __uint_as_float(w << 16); }
__device__ __forceinline__ float bf2f_hi(unsigned w) { return __uint_as_float(w & 0xFFFF0000u); }
__device__ __forceinline__ unsigned short f2bf(float f) {
    unsigned u = __float_as_uint(f);
    u += 0x7FFFu + ((u >> 16) & 1u);      // RTNE
    return (unsigned short)(u >> 16);
}
__device__ __forceinline__ float wred64(float v) {
#pragma unroll
    for (int m = 1; m < 64; m <<= 1) v += __shfl_xor(v, m, 64);
    return v;
}

// Per-block dtype self-detection (bf16-pair low halfword exponent clusters in [110,130];
// fp32 low mantissa bits hit ~8%). 256-thread blocks only. Costs one syncthreads.
__device__ __forceinline__ int self_detect(const unsigned* probe, int t) {
    __shared__ int sd_cnt[4];
    unsigned w = probe[t];
    unsigned e = (w >> 7) & 0xFFu;
    unsigned long long m = __ballot(e >= 110u && e <= 130u);
    if ((t & 63) == 0) sd_cnt[t >> 6] = __popcll(m);
    __syncthreads();
    int c = sd_cnt[0] + sd_cnt[1] + sd_cnt[2] + sd_cnt[3];
    __syncthreads();
    return c >= 128;
}

// ---------- workspace layout (bytes) ----------
#define O_SIMG   0               // 64*64 f32 (16384)
#define O_RNAN   16384           // 32768 f32 (131072)
#define O_RNBN   147456          // 32768 f32 (131072)
#define O_COLP   278528          // 2 chains x 2 banks x 64ex x 8blk x 512 u32 (4 MB)
#define O_P0     4472832         // 64*512*512 bf16 (33554432) -> total ~38 MB (proven fit)

// ---------- fused inverse L2 norms for struct_nodes + seq_tokens (65536 rows) ----------
__global__ void k_rnormAB(const void* anr, const void* bnr, float* rnan, float* rnbn) {
    int t = threadIdx.x;
    int flag = self_detect((const unsigned*)anr, t);
    int gr  = blockIdx.x * 4 + (t >> 6);      // global row 0..65535
    int lane = t & 63;
    const void* in = (gr < 32768) ? anr : bnr;
    float* rn      = (gr < 32768) ? rnan : rnbn;
    int row = gr & 32767;
    float f0, f1;
    if (flag) {
        unsigned w = ((const unsigned*)in)[row * 64 + lane];
        f0 = bf2f_lo(w); f1 = bf2f_hi(w);
    } else {
        float2 v = ((const float2*)in)[row * 64 + lane];
        f0 = v.x; f1 = v.y;
    }
    float ss = wred64(f0 * f0 + f1 * f1);
    if (lane == 0) rn[row] = 1.0f / fmaxf(sqrtf(ss), 1e-12f);
}

// ---------- global sim logits (self-detecting, self-normalizing) ----------
__global__ void k_simg(const void* sgr, const void* qgr, float* simg) {
    __shared__ float rls[128];                // [0..63]=1/||s_i||, [64..127]=1/||q_j||
    int t = threadIdx.x;
    int flag = self_detect((const unsigned*)sgr, t);
    int w = t >> 6, lane = t & 63;
    for (int rr = 0; rr < 32; rr++) {         // each wave: 32 of 128 rows
        int ri = w * 32 + rr;
        const void* base = (ri < 64) ? sgr : qgr;
        int row = ri & 63;
        float f0, f1;
        if (flag) {
            unsigned wd = ((const unsigned*)base)[row * 64 + lane];
            f0 = bf2f_lo(wd); f1 = bf2f_hi(wd);
        } else {
            float2 v = ((const float2*)base)[row * 64 + lane];
            f0 = v.x; f1 = v.y;
        }
        float ss = wred64(f0 * f0 + f1 * f1);
        if (lane == 0) rls[ri] = 1.0f / fmaxf(sqrtf(ss), 1e-12f);
    }
    __syncthreads();
    int g = blockIdx.x * 256 + t;             // 4096 = 64*64
    int i = g >> 6, j = g & 63;
    float dot = 0.f;
    if (flag) {
        const unsigned* a = (const unsigned*)sgr + i * 64;
        const unsigned* b = (const unsigned*)qgr + j * 64;
        for (int k = 0; k < 64; k++) {
            unsigned wa = a[k], wb = b[k];
            dot += bf2f_lo(wa) * bf2f_lo(wb);
            dot += bf2f_hi(wa) * bf2f_hi(wb);
        }
    } else {
        const float4* a = (const float4*)sgr + i * 32;
        const float4* b = (const float4*)qgr + j * 32;
        for (int k = 0; k < 32; k++) {
            float4 x = a[k], y = b[k];
            dot += x.x * y.x + x.y * y.y + x.z * y.z + x.w * y.w;
        }
    }
    simg[g] = dot * rls[i] * rls[64 + j] * 10.0f;   // /TEMP = *10
}

// ---------- global NT-Xent; initializes all 3 outputs (stores, not adds) ----------
__global__ void k_gloss(const float* __restrict__ simg, float* outf) {
    __shared__ float red[64];
    int i = threadIdx.x;
    if (i < 64) {
        float m = -1e30f;
        for (int j = 0; j < 64; j++) m = fmaxf(m, simg[i * 64 + j]);
        float se = 0.f;
        for (int j = 0; j < 64; j++) se += expf(simg[i * 64 + j] - m);
        float rl = simg[i * 64 + i] - (m + logf(se));
        float m2 = -1e30f;
        for (int j = 0; j < 64; j++) m2 = fmaxf(m2, simg[j * 64 + i]);
        float se2 = 0.f;
        for (int j = 0; j < 64; j++) se2 += expf(simg[j * 64 + i] - m2);
        float cl = simg[i * 64 + i] - (m2 + logf(se2));
        red[i] = rl + cl;
    }
    __syncthreads();
    if (i == 0) {
        float s = 0.f;
        for (int k = 0; k < 64; k++) s += red[k];
        float g = -s / 128.0f;
        outf[0] = g;          // global loss
        outf[1] = 0.0f;       // local loss accumulated by k_persist
        outf[2] = g;          // total = g + local (added by k_persist)
    }
}

// ---------- build P0 = exp(10*sim) bf16, per-example 512x512, 128x128 tiles ----------
__global__ void k_build(const void* anr, const void* bnr, const float* rnan, const float* rnbn,
                        unsigned short* p0) {
    int t  = threadIdx.x;
    int flag = self_detect((const unsigned*)anr, t);
    int b   = blockIdx.y;
    int r0t = (blockIdx.x >> 2) * 128;
    int c0t = (blockIdx.x & 3) * 128;
    __shared__ float As[128][33];
    __shared__ float Bs[128][33];
    int tr = t >> 4, tc = t & 15;
    float acc[8][8];
#pragma unroll
    for (int i = 0; i < 8; i++)
#pragma unroll
        for (int j = 0; j < 8; j++) acc[i][j] = 0.f;

    for (int kc = 0; kc < 4; kc++) {            // K chunks of 32
        for (int ii = 0; ii < 4; ii++) {
            int idx = t + 256 * ii;             // 0..1023 -> 128 rows x 8 float4
            int r = idx >> 3, c4 = idx & 7;
            {   // A chunk (struct_nodes)
                int grow = b * NP + r0t + r;
                float sc = rnan[grow];
                float f0, f1, f2, f3;
                if (flag) {
                    const unsigned* src = (const unsigned*)anr + ((grow * DIMD + kc * 32 + c4 * 4) >> 1);
                    unsigned w0 = src[0], w1 = src[1];
                    f0 = bf2f_lo(w0); f1 = bf2f_hi(w0); f2 = bf2f_lo(w1); f3 = bf2f_hi(w1);
                } else {
                    float4 v = *((const float4*)((const float*)anr + grow * DIMD + kc * 32 + c4 * 4));
                    f0 = v.x; f1 = v.y; f2 = v.z; f3 = v.w;
                }
                As[r][c4 * 4 + 0] = f0 * sc; As[r][c4 * 4 + 1] = f1 * sc;
                As[r][c4 * 4 + 2] = f2 * sc; As[r][c4 * 4 + 3] = f3 * sc;
            }
            {   // B chunk (seq_tokens)
                int grow = b * NP + c0t + r;
                float sc = rnbn[grow];
                float f0, f1, f2, f3;
                if (flag) {
                    const unsigned* src = (const unsigned*)bnr + ((grow * DIMD + kc * 32 + c4 * 4) >> 1);
                    unsigned w0 = src[0], w1 = src[1];
                    f0 = bf2f_lo(w0); f1 = bf2f_hi(w0); f2 = bf2f_lo(w1); f3 = bf2f_hi(w1);
                } else {
                    float4 v = *((const float4*)((const float*)bnr + grow * DIMD + kc * 32 + c4 * 4));
                    f0 = v.x; f1 = v.y; f2 = v.z; f3 = v.w;
                }
                Bs[r][c4 * 4 + 0] = f0 * sc; Bs[r][c4 * 4 + 1] = f1 * sc;
                Bs[r][c4 * 4 + 2] = f2 * sc; Bs[r][c4 * 4 + 3] = f3 * sc;
            }
        }
        __syncthreads();
        for (int kk = 0; kk < 32; kk++) {
            float av[8], bv[8];
#pragma unroll
            for (int i = 0; i < 8; i++) av[i] = As[tr * 8 + i][kk];
#pragma unroll
            for (int j = 0; j < 8; j++) bv[j] = Bs[tc * 8 + j][kk];
#pragma unroll
            for (int i = 0; i < 8; i++)
#pragma unroll
                for (int j = 0; j < 8; j++) acc[i][j] += av[i] * bv[j];
        }
        __syncthreads();
    }
#pragma unroll
    for (int i = 0; i < 8; i++) {
        int grow = b * NP + r0t + tr * 8 + i;
        unsigned short h[8];
#pragma unroll
        for (int j = 0; j < 8; j++) h[j] = f2bf(expf(acc[i][j] * 10.0f));   // exp(sim/REG)
        uint4 pk;
        pk.x = (unsigned)h[0] | ((unsigned)h[1] << 16);
        pk.y = (unsigned)h[2] | ((unsigned)h[3] << 16);
        pk.z = (unsigned)h[4] | ((unsigned)h[5] << 16);
        pk.w = (unsigned)h[6] | ((unsigned)h[7] << 16);
        *((uint4*)(p0 + ((size_t)grow * NP + c0t + tc * 8))) = pk;
    }
}

// ---------- persistent Sinkhorn: DUAL-CHAIN interleave on R8's no-spill layout ----------
// R9 lesson: whole-example-in-registers is physically impossible (needs >=192 VGPR/thread
// at 1024 thr; budget 128). So run BOTH Jacobi chains in the same 8 blocks/example:
//   chain U (computes u_100): v'_{2s+1}=b/(P0^T u_2s);  u_{2s+2}=a/(P0 v'_{2s+1})
//   chain V (computes v_100): u'_{2s+1}=a/(P0 v_2s);    v_{2s+2}=b/(P0^T u'_{2s+1})
// Double-step schedule (one exchange window covered by the OTHER chain's local work):
//   1. colpass U -> credU; syncA
//   2. store U (tag s+1); rowpass V (local)          <- store U drains during 2-3
//   3. colpass V -> credV; syncB
//   4. poll U -> v_sU; syncC                         <- no store adjacent to poll/sync
//   5. store V; rowpass U (local)                    <- store V drains during rowpass U
//   6. poll V -> v_sV; syncD
// This removes both R8 stall mechanisms: store->poll visibility gap is ~2 us of compute,
// and no poll/sync waits on a just-fired store's fabric ack (vmcnt drain, R4/m97 lesson).
// Deadlock-free: poll U needs only step-2 stores (unconditional); poll V needs step-5
// stores which only need poll U. Mod-2 banks safe: a block overwriting bank (s&1) at ds
// s+2 must have passed its ds s+1 poll, which requires ALL blocks past their ds s polls
// (transitively: all readers of the slot are done). Tags 1..50; stale 0xAA ws = 0xAAAA
// never matches. Bonus: u_100 (regs) and v_100 (LDS) end in the SAME block -> the final
// contraction needs no cross-block publication.
// Resources: pw[16] uint4 = 64 VGPR + uU/uV 32 + working ~50 -> ~150, budget 256 at
// launch_bounds(256,2). LDS ~20.5 KB, 2 blocks/CU -> all 512 blocks co-resident (proven).
__global__ __launch_bounds__(256, 2) void k_persist(const unsigned short* __restrict__ p0,
                                                    unsigned* __restrict__ colp,
                                                    float* __restrict__ outf) {
    int blk = blockIdx.x;
    int rb  = blk >> 6;         // 0..7
    int b   = blk & 63;         // example
    int rowbase = rb * 64;
    int t = threadIdx.x, w = t >> 6, lane = t & 63;

    __shared__ float credU[4][512];
    __shared__ float credV[4][512];
    __shared__ float v_sU[512];
    __shared__ float v_sV[512];
    __shared__ float bs[4];

    // load this lane's static P0 slice into registers (only global P0 read of the kernel)
    uint4 pw[16];
#pragma unroll
    for (int r = 0; r < 16; r++) {
        int row = rowbase + w * 16 + r;
        pw[r] = ((const uint4*)(p0 + (((size_t)(b << 9) + row) << 9)))[lane];
    }
    float uU[16], uV[16];
#pragma unroll
    for (int r = 0; r < 16; r++) uU[r] = MARG;     // u_0 = a
    int col0 = t, col1 = t + 256;
    v_sV[col0] = MARG; v_sV[col1] = MARG;          // v_0 = b
    __syncthreads();

#pragma unroll 1
    for (int s = 0; s < 50; ++s) {
        unsigned tag = (unsigned)(s + 1);
        int bank = s & 1;
        // ---- 1. col pass chain U (P0^T u_2s partials) ----
        {
            float ca[8];
#pragma unroll
            for (int k = 0; k < 8; ++k) ca[k] = 0.f;
#pragma unroll
            for (int r = 0; r < 16; ++r) {
                float u_r = uU[r];
                uint4 pv = pw[r];
                ca[0] += bf2f_lo(pv.x) * u_r; ca[1] += bf2f_hi(pv.x) * u_r;
                ca[2] += bf2f_lo(pv.y) * u_r; ca[3] += bf2f_hi(pv.y) * u_r;
                ca[4] += bf2f_lo(pv.z) * u_r; ca[5] += bf2f_hi(pv.z) * u_r;
                ca[6] += bf2f_lo(pv.w) * u_r; ca[7] += bf2f_hi(pv.w) * u_r;
            }
#pragma unroll
            for (int k = 0; k < 8; ++k) credU[w][lane * 8 + k] = ca[k];
        }
        __syncthreads();   // A: credU ready
        // ---- 2. store U (fire-and-forget), then rowpass V (local) ----
        {
            float s0 = credU[0][col0] + credU[1][col0] + credU[2][col0] + credU[3][col0];
            float s1 = credU[0][col1] + credU[1][col1] + credU[2][col1] + credU[3][col1];
            unsigned pk0 = ((unsigned)f2bf(s0) << 16) | tag;
            unsigned pk1 = ((unsigned)f2bf(s1) << 16) | tag;
            unsigned* cw = colp + ((((bank * 64 + b) * 8 + rb) << 9));          // chain U
            __hip_atomic_store(&cw[col0], pk0, __ATOMIC_RELAXED, __HIP_MEMORY_SCOPE_AGENT);
            __hip_atomic_store(&cw[col1], pk1, __ATOMIC_RELAXED, __HIP_MEMORY_SCOPE_AGENT);
        }
        {   // rowpass V: u'_{2s+1} = a/(P0 v_2s)
            float vr[8];
#pragma unroll
            for (int k = 0; k < 8; ++k) vr[k] = v_sV[lane * 8 + k];
#pragma unroll
            for (int r = 0; r < 16; ++r) {
                uint4 pv = pw[r];
                float rd = bf2f_lo(pv.x) * vr[0] + bf2f_hi(pv.x) * vr[1]
                         + bf2f_lo(pv.y) * vr[2] + bf2f_hi(pv.y) * vr[3]
                         + bf2f_lo(pv.z) * vr[4] + bf2f_hi(pv.z) * vr[5]
                         + bf2f_lo(pv.w) * vr[6] + bf2f_hi(pv.w) * vr[7];
                rd = wred64(rd);
                float q = MARG / rd;
                if (!isfinite(q)) q = MARG;
                uV[r] = q;
            }
        }
        // ---- 3. col pass chain V (P0^T u'_{2s+1} partials) ----
        {
            float ca[8];
#pragma unroll
            for (int k = 0; k < 8; ++k) ca[k] = 0.f;
#pragma unroll
            for (int r = 0; r < 16; ++r) {
                float u_r = uV[r];
                uint4 pv = pw[r];
                ca[0] += bf2f_lo(pv.x) * u_r; ca[1] += bf2f_hi(pv.x) * u_r;
                ca[2] += bf2f_lo(pv.y) * u_r; ca[3] += bf2f_hi(pv.y) * u_r;
                ca[4] += bf2f_lo(pv.z) * u_r; ca[5] += bf2f_hi(pv.z) * u_r;
                ca[6] += bf2f_lo(pv.w) * u_r; ca[7] += bf2f_hi(pv.w) * u_r;
            }
#pragma unroll
            for (int k = 0; k < 8; ++k) credV[w][lane * 8 + k] = ca[k];
        }
        __syncthreads();   // B: credV ready (store U long gone from the queue)
        // ---- 4. poll chain U -> v_sU ----
        {
            const unsigned* crd = colp + (((bank * 64 + b) * 8) << 9);          // chain U
            unsigned got0[8], got1[8];
            for (;;) {
                bool o = true;
#pragma unroll
                for (int p = 0; p < 8; p++) {
                    got0[p] = __hip_atomic_load(&crd[(p << 9) + col0], __ATOMIC_RELAXED,
                                                __HIP_MEMORY_SCOPE_AGENT);
                    got1[p] = __hip_atomic_load(&crd[(p << 9) + col1], __ATOMIC_RELAXED,
                                                __HIP_MEMORY_SCOPE_AGENT);
                }
#pragma unroll
                for (int p = 0; p < 8; p++)
                    o = o && ((got0[p] & 0xFFFFu) == tag) && ((got1[p] & 0xFFFFu) == tag);
                if (o) break;
                __builtin_amdgcn_s_sleep(1);
            }
            float r0 = 0.f, r1 = 0.f;
#pragma unroll
            for (int p = 0; p < 8; p++) {
                r0 += __uint_as_float(got0[p] & 0xFFFF0000u);
                r1 += __uint_as_float(got1[p] & 0xFFFF0000u);
            }
            float q0 = MARG / r0; if (!isfinite(q0)) q0 = MARG;
            float q1 = MARG / r1; if (!isfinite(q1)) q1 = MARG;
            v_sU[col0] = q0;
            v_sU[col1] = q1;
        }
        __syncthreads();   // C: v_sU ready (no store in flight)
        // ---- 5. store V, then rowpass U (local) ----
        {
            float s0 = credV[0][col0] + credV[1][col0] + credV[2][col0] + credV[3][col0];
            float s1 = credV[0][col1] + credV[1][col1] + credV[2][col1] + credV[3][col1];
            unsigned pk0 = ((unsigned)f2bf(s0) << 16) | tag;
            unsigned pk1 = ((unsigned)f2bf(s1) << 16) | tag;
            unsigned* cw = colp + (((((2 + bank) * 64 + b) * 8 + rb) << 9));    // chain V
            __hip_atomic_store(&cw[col0], pk0, __ATOMIC_RELAXED, __HIP_MEMORY_SCOPE_AGENT);
            __hip_atomic_store(&cw[col1], pk1, __ATOMIC_RELAXED, __HIP_MEMORY_SCOPE_AGENT);
        }
        {   // rowpass U: u_{2s+2} = a/(P0 v'_{2s+1})
            float vr[8];
#pragma unroll
            for (int k = 0; k < 8; ++k) vr[k] = v_sU[lane * 8 + k];
#pragma unroll
            for (int r = 0; r < 16; ++r) {
                uint4 pv = pw[r];
                float rd = bf2f_lo(pv.x) * vr[0] + bf2f_hi(pv.x) * vr[1]
                         + bf2f_lo(pv.y) * vr[2] + bf2f_hi(pv.y) * vr[3]
                         + bf2f_lo(pv.z) * vr[4] + bf2f_hi(pv.z) * vr[5]
                         + bf2f_lo(pv.w) * vr[6] + bf2f_hi(pv.w) * vr[7];
                rd = wred64(rd);
                float q = MARG / rd;
                if (!isfinite(q)) q = MARG;
                uU[r] = q;
            }
        }
        // ---- 6. poll chain V -> v_sV ----
        {
            const unsigned* crd = colp + ((((2 + bank) * 64 + b) * 8) << 9);    // chain V
            unsigned got0[8], got1[8];
            for (;;) {
                bool o = true;
#pragma unroll
                for (int p = 0; p < 8; p++) {
                    got0[p] = __hip_atomic_load(&crd[(p << 9) + col0], __ATOMIC_RELAXED,
                                                __HIP_MEMORY_SCOPE_AGENT);
                    got1[p] = __hip_atomic_load(&crd[(p << 9) + col1], __ATOMIC_RELAXED,
                                                __HIP_MEMORY_SCOPE_AGENT);
                }
#pragma unroll
                for (int p = 0; p < 8; p++)
                    o = o && ((got0[p] & 0xFFFFu) == tag) && ((got1[p] & 0xFFFFu) == tag);
                if (o) break;
                __builtin_amdgcn_s_sleep(1);
            }
            float r0 = 0.f, r1 = 0.f;
#pragma unroll
            for (int p = 0; p < 8; p++) {
                r0 += __uint_as_float(got0[p] & 0xFFFF0000u);
                r1 += __uint_as_float(got1[p] & 0xFFFF0000u);
            }
            float q0 = MARG / r0; if (!isfinite(q0)) q0 = MARG;
            float q1 = MARG / r1; if (!isfinite(q1)) q1 = MARG;
            v_sV[col0] = q0;
            v_sV[col1] = q1;
        }
        __syncthreads();   // D: v_sV ready for next double-step
    }

    // ---- final contraction: u_100 (uU regs) x v_100 (v_sV) ; C = -0.1*log(P0) ----
    float vr[8];
#pragma unroll
    for (int k = 0; k < 8; ++k) vr[k] = v_sV[lane * 8 + k];
    float acc = 0.f;
#pragma unroll
    for (int r = 0; r < 16; ++r) {
        float u_r = uU[r];
        uint4 pv = pw[r];
        float f[8];
        f[0] = bf2f_lo(pv.x); f[1] = bf2f_hi(pv.x);
        f[2] = bf2f_lo(pv.y); f[3] = bf2f_hi(pv.y);
        f[4] = bf2f_lo(pv.z); f[5] = bf2f_hi(pv.z);
        f[6] = bf2f_lo(pv.w); f[7] = bf2f_hi(pv.w);
#pragma unroll
        for (int k = 0; k < 8; ++k) {
            float p = f[k];
            acc += u_r * p * vr[k] * (-0.1f) * logf(p);
        }
    }
    acc = wred64(acc);
    if (lane == 0) bs[w] = acc;
    __syncthreads();
    if (t == 0) {
        float c = (bs[0] + bs[1] + bs[2] + bs[3]) * (1.0f / 64.0f);   // /B
        atomicAdd(&outf[1], c);
        atomicAdd(&outf[2], c);
    }
}

extern "C" void kernel_launch(void* const* d_in, const int* in_sizes, int n_in,
                              void* d_out, int out_size, void* d_ws, size_t ws_size,
                              hipStream_t stream) {
    const void* sg = d_in[0];
    const void* qg = d_in[1];
    const void* an = d_in[2];
    const void* bn = d_in[3];
    char* ws = (char*)d_ws;
    float* outf = (float*)d_out;                     // output dtype: float32 x3

    float* simg     = (float*)(ws + O_SIMG);
    float* rnan     = (float*)(ws + O_RNAN);
    float* rnbn     = (float*)(ws + O_RNBN);
    unsigned* colp  = (unsigned*)(ws + O_COLP);      // 2 chains x 2 tagged banks
    unsigned short* p0 = (unsigned short*)(ws + O_P0);

    k_rnormAB<<<16384, 256, 0, stream>>>(an, bn, rnan, rnbn);
    k_simg<<<16, 256, 0, stream>>>(sg, qg, simg);
    k_gloss<<<1, 256, 0, stream>>>(simg, outf);
    k_build<<<dim3(16, 64), 256, 0, stream>>>(an, bn, rnan, rnbn, p0);
    k_persist<<<512, 256, 0, stream>>>(p0, colp, outf);
}

// Round 11
// 776.119 us; speedup vs baseline: 4.8504x; 1.9712x over previous
//
#include <hip/hip_runtime.h>
#include <cstdint>
#include <cmath>

// Problem constants (fixed by reference):
//   B=64 examples, D=128 dim, NP=512 nodes/tokens per example, 100 Jacobi Sinkhorn iters.
#define NB_EX 64
#define DIMD 128
#define NP 512
constexpr float MARG = 1.0f / 512.0f;   // a = b = 1/n

// ---------- helpers ----------
__device__ __forceinline__ float bf2f_lo(unsigned w) { return __uint_as_float(w << 16); }
__device__ __forceinline__ float bf2f_hi(unsigned w) { return __uint_as_float(w & 0xFFFF0000u); }
__device__ __forceinline__ unsigned short f2bf(float f) {
    unsigned u = __float_as_uint(f);
    u += 0x7FFFu + ((u >> 16) & 1u);      // RTNE
    return (unsigned short)(u >> 16);
}
__device__ __forceinline__ float wred64(float v) {
#pragma unroll
    for (int m = 1; m < 64; m <<= 1) v += __shfl_xor(v, m, 64);
    return v;
}

// Per-block dtype self-detection (bf16-pair low halfword exponent clusters in [110,130];
// fp32 low mantissa bits hit ~8%). 256-thread blocks only. Costs one syncthreads.
__device__ __forceinline__ int self_detect(const unsigned* probe, int t) {
    __shared__ int sd_cnt[4];
    unsigned w = probe[t];
    unsigned e = (w >> 7) & 0xFFu;
    unsigned long long m = __ballot(e >= 110u && e <= 130u);
    if ((t & 63) == 0) sd_cnt[t >> 6] = __popcll(m);
    __syncthreads();
    int c = sd_cnt[0] + sd_cnt[1] + sd_cnt[2] + sd_cnt[3];
    __syncthreads();
    return c >= 128;
}

// ---------- workspace layout (bytes) ----------
#define O_SIMG   0               // 64*64 f32 (16384)
#define O_RNAN   16384           // 32768 f32 (131072)
#define O_RNBN   147456          // 32768 f32 (131072)
#define O_COLP   278528          // 2 chains x 2 banks x 64ex x 8blk x 512 u32 (4 MB)
#define O_P0     4472832         // 64*512*512 bf16 (33554432) -> total ~38 MB (proven fit)

// ---------- fused inverse L2 norms for struct_nodes + seq_tokens (65536 rows) ----------
__global__ void k_rnormAB(const void* anr, const void* bnr, float* rnan, float* rnbn) {
    int t = threadIdx.x;
    int flag = self_detect((const unsigned*)anr, t);
    int gr  = blockIdx.x * 4 + (t >> 6);      // global row 0..65535
    int lane = t & 63;
    const void* in = (gr < 32768) ? anr : bnr;
    float* rn      = (gr < 32768) ? rnan : rnbn;
    int row = gr & 32767;
    float f0, f1;
    if (flag) {
        unsigned w = ((const unsigned*)in)[row * 64 + lane];
        f0 = bf2f_lo(w); f1 = bf2f_hi(w);
    } else {
        float2 v = ((const float2*)in)[row * 64 + lane];
        f0 = v.x; f1 = v.y;
    }
    float ss = wred64(f0 * f0 + f1 * f1);
    if (lane == 0) rn[row] = 1.0f / fmaxf(sqrtf(ss), 1e-12f);
}

// ---------- global sim logits (self-detecting, self-normalizing) ----------
__global__ void k_simg(const void* sgr, const void* qgr, float* simg) {
    __shared__ float rls[128];                // [0..63]=1/||s_i||, [64..127]=1/||q_j||
    int t = threadIdx.x;
    int flag = self_detect((const unsigned*)sgr, t);
    int w = t >> 6, lane = t & 63;
    for (int rr = 0; rr < 32; rr++) {         // each wave: 32 of 128 rows
        int ri = w * 32 + rr;
        const void* base = (ri < 64) ? sgr : qgr;
        int row = ri & 63;
        float f0, f1;
        if (flag) {
            unsigned wd = ((const unsigned*)base)[row * 64 + lane];
            f0 = bf2f_lo(wd); f1 = bf2f_hi(wd);
        } else {
            float2 v = ((const float2*)base)[row * 64 + lane];
            f0 = v.x; f1 = v.y;
        }
        float ss = wred64(f0 * f0 + f1 * f1);
        if (lane == 0) rls[ri] = 1.0f / fmaxf(sqrtf(ss), 1e-12f);
    }
    __syncthreads();
    int g = blockIdx.x * 256 + t;             // 4096 = 64*64
    int i = g >> 6, j = g & 63;
    float dot = 0.f;
    if (flag) {
        const unsigned* a = (const unsigned*)sgr + i * 64;
        const unsigned* b = (const unsigned*)qgr + j * 64;
        for (int k = 0; k < 64; k++) {
            unsigned wa = a[k], wb = b[k];
            dot += bf2f_lo(wa) * bf2f_lo(wb);
            dot += bf2f_hi(wa) * bf2f_hi(wb);
        }
    } else {
        const float4* a = (const float4*)sgr + i * 32;
        const float4* b = (const float4*)qgr + j * 32;
        for (int k = 0; k < 32; k++) {
            float4 x = a[k], y = b[k];
            dot += x.x * y.x + x.y * y.y + x.z * y.z + x.w * y.w;
        }
    }
    simg[g] = dot * rls[i] * rls[64 + j] * 10.0f;   // /TEMP = *10
}

// ---------- global NT-Xent; initializes all 3 outputs (stores, not adds) ----------
__global__ void k_gloss(const float* __restrict__ simg, float* outf) {
    __shared__ float red[64];
    int i = threadIdx.x;
    if (i < 64) {
        float m = -1e30f;
        for (int j = 0; j < 64; j++) m = fmaxf(m, simg[i * 64 + j]);
        float se = 0.f;
        for (int j = 0; j < 64; j++) se += expf(simg[i * 64 + j] - m);
        float rl = simg[i * 64 + i] - (m + logf(se));
        float m2 = -1e30f;
        for (int j = 0; j < 64; j++) m2 = fmaxf(m2, simg[j * 64 + i]);
        float se2 = 0.f;
        for (int j = 0; j < 64; j++) se2 += expf(simg[j * 64 + i] - m2);
        float cl = simg[i * 64 + i] - (m2 + logf(se2));
        red[i] = rl + cl;
    }
    __syncthreads();
    if (i == 0) {
        float s = 0.f;
        for (int k = 0; k < 64; k++) s += red[k];
        float g = -s / 128.0f;
        outf[0] = g;          // global loss
        outf[1] = 0.0f;       // local loss accumulated by k_persist
        outf[2] = g;          // total = g + local (added by k_persist)
    }
}

// ---------- build P0 = exp(10*sim) bf16, per-example 512x512, 128x128 tiles ----------
__global__ void k_build(const void* anr, const void* bnr, const float* rnan, const float* rnbn,
                        unsigned short* p0) {
    int t  = threadIdx.x;
    int flag = self_detect((const unsigned*)anr, t);
    int b   = blockIdx.y;
    int r0t = (blockIdx.x >> 2) * 128;
    int c0t = (blockIdx.x & 3) * 128;
    __shared__ float As[128][33];
    __shared__ float Bs[128][33];
    int tr = t >> 4, tc = t & 15;
    float acc[8][8];
#pragma unroll
    for (int i = 0; i < 8; i++)
#pragma unroll
        for (int j = 0; j < 8; j++) acc[i][j] = 0.f;

    for (int kc = 0; kc < 4; kc++) {            // K chunks of 32
        for (int ii = 0; ii < 4; ii++) {
            int idx = t + 256 * ii;             // 0..1023 -> 128 rows x 8 float4
            int r = idx >> 3, c4 = idx & 7;
            {   // A chunk (struct_nodes)
                int grow = b * NP + r0t + r;
                float sc = rnan[grow];
                float f0, f1, f2, f3;
                if (flag) {
                    const unsigned* src = (const unsigned*)anr + ((grow * DIMD + kc * 32 + c4 * 4) >> 1);
                    unsigned w0 = src[0], w1 = src[1];
                    f0 = bf2f_lo(w0); f1 = bf2f_hi(w0); f2 = bf2f_lo(w1); f3 = bf2f_hi(w1);
                } else {
                    float4 v = *((const float4*)((const float*)anr + grow * DIMD + kc * 32 + c4 * 4));
                    f0 = v.x; f1 = v.y; f2 = v.z; f3 = v.w;
                }
                As[r][c4 * 4 + 0] = f0 * sc; As[r][c4 * 4 + 1] = f1 * sc;
                As[r][c4 * 4 + 2] = f2 * sc; As[r][c4 * 4 + 3] = f3 * sc;
            }
            {   // B chunk (seq_tokens)
                int grow = b * NP + c0t + r;
                float sc = rnbn[grow];
                float f0, f1, f2, f3;
                if (flag) {
                    const unsigned* src = (const unsigned*)bnr + ((grow * DIMD + kc * 32 + c4 * 4) >> 1);
                    unsigned w0 = src[0], w1 = src[1];
                    f0 = bf2f_lo(w0); f1 = bf2f_hi(w0); f2 = bf2f_lo(w1); f3 = bf2f_hi(w1);
                } else {
                    float4 v = *((const float4*)((const float*)bnr + grow * DIMD + kc * 32 + c4 * 4));
                    f0 = v.x; f1 = v.y; f2 = v.z; f3 = v.w;
                }
                Bs[r][c4 * 4 + 0] = f0 * sc; Bs[r][c4 * 4 + 1] = f1 * sc;
                Bs[r][c4 * 4 + 2] = f2 * sc; Bs[r][c4 * 4 + 3] = f3 * sc;
            }
        }
        __syncthreads();
        for (int kk = 0; kk < 32; kk++) {
            float av[8], bv[8];
#pragma unroll
            for (int i = 0; i < 8; i++) av[i] = As[tr * 8 + i][kk];
#pragma unroll
            for (int j = 0; j < 8; j++) bv[j] = Bs[tc * 8 + j][kk];
#pragma unroll
            for (int i = 0; i < 8; i++)
#pragma unroll
                for (int j = 0; j < 8; j++) acc[i][j] += av[i] * bv[j];
        }
        __syncthreads();
    }
#pragma unroll
    for (int i = 0; i < 8; i++) {
        int grow = b * NP + r0t + tr * 8 + i;
        unsigned short h[8];
#pragma unroll
        for (int j = 0; j < 8; j++) h[j] = f2bf(expf(acc[i][j] * 10.0f));   // exp(sim/REG)
        uint4 pk;
        pk.x = (unsigned)h[0] | ((unsigned)h[1] << 16);
        pk.y = (unsigned)h[2] | ((unsigned)h[3] << 16);
        pk.z = (unsigned)h[4] | ((unsigned)h[5] << 16);
        pk.w = (unsigned)h[6] | ((unsigned)h[7] << 16);
        *((uint4*)(p0 + ((size_t)grow * NP + c0t + tc * 8))) = pk;
    }
}

// ---------- persistent Sinkhorn: dual-chain interleave, u-vectors in LDS (no spill) ----------
// R10 lesson: dual-chain with uU[16]+uV[16] in registers = 140 persistent VGPRs > the 128
// the compiler allocates -> full scratch spill (FETCH 2.6 GB, VALU 17%). Fix: u vectors
// live in LDS (u_sU[64], u_sV[64]); they are WAVE-LOCAL (wave w writes its 16 rows after
// wred64, only wave w reads them) so no new barriers — same-wave LDS RAW is lgkmcnt-only.
// Persistent registers = pw[16] uint4 = 64; transient peak ~100 < 128. Schedule unchanged
// from R10 (which was numerically exact):
//   1. colpass U -> credU; syncA
//   2. store U (tag s+1); rowpass V (u_sV, local)    <- store U drains under 2-3
//   3. colpass V -> credV; syncB
//   4. poll U -> v_sU; syncC                          <- no store adjacent to poll/sync
//   5. store V; rowpass U (u_sU, local)               <- store V drains under rowpass U
//   6. poll V -> v_sV; syncD
// Deadlock/bank proofs as R10. Tags 1..50; 0xAA-poisoned stale ws (0xAAAA) never matches.
// u_100 (u_sU) and v_100 (v_sV) end in the SAME block -> contraction needs no exchange.
__global__ __launch_bounds__(256, 2) void k_persist(const unsigned short* __restrict__ p0,
                                                    unsigned* __restrict__ colp,
                                                    float* __restrict__ outf) {
    int blk = blockIdx.x;
    int rb  = blk >> 6;         // 0..7
    int b   = blk & 63;         // example
    int rowbase = rb * 64;
    int t = threadIdx.x, w = t >> 6, lane = t & 63;

    __shared__ float credU[4][512];
    __shared__ float credV[4][512];
    __shared__ float v_sU[512];
    __shared__ float v_sV[512];
    __shared__ float u_sU[64];
    __shared__ float u_sV[64];
    __shared__ float bs[4];

    // load this lane's static P0 slice into registers (only global P0 read of the kernel)
    uint4 pw[16];
#pragma unroll
    for (int r = 0; r < 16; r++) {
        int row = rowbase + w * 16 + r;
        pw[r] = ((const uint4*)(p0 + (((size_t)(b << 9) + row) << 9)))[lane];
    }
    int col0 = t, col1 = t + 256;
    if (t < 64) u_sU[t] = MARG;                    // u_0 = a
    v_sV[col0] = MARG; v_sV[col1] = MARG;          // v_0 = b
    __syncthreads();

#pragma unroll 1
    for (int s = 0; s < 50; ++s) {
        unsigned tag = (unsigned)(s + 1);
        int bank = s & 1;
        // ---- 1. col pass chain U (P0^T u_2s partials) ----
        {
            float ca[8];
#pragma unroll
            for (int k = 0; k < 8; ++k) ca[k] = 0.f;
#pragma unroll
            for (int r = 0; r < 16; ++r) {
                float u_r = u_sU[w * 16 + r];      // broadcast LDS read
                uint4 pv = pw[r];
                ca[0] += bf2f_lo(pv.x) * u_r; ca[1] += bf2f_hi(pv.x) * u_r;
                ca[2] += bf2f_lo(pv.y) * u_r; ca[3] += bf2f_hi(pv.y) * u_r;
                ca[4] += bf2f_lo(pv.z) * u_r; ca[5] += bf2f_hi(pv.z) * u_r;
                ca[6] += bf2f_lo(pv.w) * u_r; ca[7] += bf2f_hi(pv.w) * u_r;
            }
#pragma unroll
            for (int k = 0; k < 8; ++k) credU[w][lane * 8 + k] = ca[k];
        }
        __syncthreads();   // A: credU ready
        // ---- 2. store U (fire-and-forget), then rowpass V (local) ----
        {
            float s0 = credU[0][col0] + credU[1][col0] + credU[2][col0] + credU[3][col0];
            float s1 = credU[0][col1] + credU[1][col1] + credU[2][col1] + credU[3][col1];
            unsigned pk0 = ((unsigned)f2bf(s0) << 16) | tag;
            unsigned pk1 = ((unsigned)f2bf(s1) << 16) | tag;
            unsigned* cw = colp + ((((bank * 64 + b) * 8 + rb) << 9));          // chain U
            __hip_atomic_store(&cw[col0], pk0, __ATOMIC_RELAXED, __HIP_MEMORY_SCOPE_AGENT);
            __hip_atomic_store(&cw[col1], pk1, __ATOMIC_RELAXED, __HIP_MEMORY_SCOPE_AGENT);
        }
        {   // rowpass V: u'_{2s+1} = a/(P0 v_2s) -> u_sV (wave-local)
            float vr[8];
#pragma unroll
            for (int k = 0; k < 8; ++k) vr[k] = v_sV[lane * 8 + k];
#pragma unroll
            for (int r = 0; r < 16; ++r) {
                uint4 pv = pw[r];
                float rd = bf2f_lo(pv.x) * vr[0] + bf2f_hi(pv.x) * vr[1]
                         + bf2f_lo(pv.y) * vr[2] + bf2f_hi(pv.y) * vr[3]
                         + bf2f_lo(pv.z) * vr[4] + bf2f_hi(pv.z) * vr[5]
                         + bf2f_lo(pv.w) * vr[6] + bf2f_hi(pv.w) * vr[7];
                rd = wred64(rd);
                float q = MARG / rd;
                if (!isfinite(q)) q = MARG;
                if (lane == 0) u_sV[w * 16 + r] = q;
            }
        }
        // ---- 3. col pass chain V (P0^T u'_{2s+1} partials) ----
        {
            float ca[8];
#pragma unroll
            for (int k = 0; k < 8; ++k) ca[k] = 0.f;
#pragma unroll
            for (int r = 0; r < 16; ++r) {
                float u_r = u_sV[w * 16 + r];      // same-wave RAW, lgkmcnt only
                uint4 pv = pw[r];
                ca[0] += bf2f_lo(pv.x) * u_r; ca[1] += bf2f_hi(pv.x) * u_r;
                ca[2] += bf2f_lo(pv.y) * u_r; ca[3] += bf2f_hi(pv.y) * u_r;
                ca[4] += bf2f_lo(pv.z) * u_r; ca[5] += bf2f_hi(pv.z) * u_r;
                ca[6] += bf2f_lo(pv.w) * u_r; ca[7] += bf2f_hi(pv.w) * u_r;
            }
#pragma unroll
            for (int k = 0; k < 8; ++k) credV[w][lane * 8 + k] = ca[k];
        }
        __syncthreads();   // B: credV ready (store U long gone)
        // ---- 4. poll chain U -> v_sU ----
        {
            const unsigned* crd = colp + (((bank * 64 + b) * 8) << 9);          // chain U
            unsigned got0[8], got1[8];
            for (;;) {
                bool o = true;
#pragma unroll
                for (int p = 0; p < 8; p++) {
                    got0[p] = __hip_atomic_load(&crd[(p << 9) + col0], __ATOMIC_RELAXED,
                                                __HIP_MEMORY_SCOPE_AGENT);
                    got1[p] = __hip_atomic_load(&crd[(p << 9) + col1], __ATOMIC_RELAXED,
                                                __HIP_MEMORY_SCOPE_AGENT);
                }
#pragma unroll
                for (int p = 0; p < 8; p++)
                    o = o && ((got0[p] & 0xFFFFu) == tag) && ((got1[p] & 0xFFFFu) == tag);
                if (o) break;
                __builtin_amdgcn_s_sleep(1);
            }
            float r0 = 0.f, r1 = 0.f;
#pragma unroll
            for (int p = 0; p < 8; p++) {
                r0 += __uint_as_float(got0[p] & 0xFFFF0000u);
                r1 += __uint_as_float(got1[p] & 0xFFFF0000u);
            }
            float q0 = MARG / r0; if (!isfinite(q0)) q0 = MARG;
            float q1 = MARG / r1; if (!isfinite(q1)) q1 = MARG;
            v_sU[col0] = q0;
            v_sU[col1] = q1;
        }
        __syncthreads();   // C: v_sU ready (no store in flight)
        // ---- 5. store V, then rowpass U (local) ----
        {
            float s0 = credV[0][col0] + credV[1][col0] + credV[2][col0] + credV[3][col0];
            float s1 = credV[0][col1] + credV[1][col1] + credV[2][col1] + credV[3][col1];
            unsigned pk0 = ((unsigned)f2bf(s0) << 16) | tag;
            unsigned pk1 = ((unsigned)f2bf(s1) << 16) | tag;
            unsigned* cw = colp + (((((2 + bank) * 64 + b) * 8 + rb) << 9));    // chain V
            __hip_atomic_store(&cw[col0], pk0, __ATOMIC_RELAXED, __HIP_MEMORY_SCOPE_AGENT);
            __hip_atomic_store(&cw[col1], pk1, __ATOMIC_RELAXED, __HIP_MEMORY_SCOPE_AGENT);
        }
        {   // rowpass U: u_{2s+2} = a/(P0 v'_{2s+1}) -> u_sU (wave-local)
            float vr[8];
#pragma unroll
            for (int k = 0; k < 8; ++k) vr[k] = v_sU[lane * 8 + k];
#pragma unroll
            for (int r = 0; r < 16; ++r) {
                uint4 pv = pw[r];
                float rd = bf2f_lo(pv.x) * vr[0] + bf2f_hi(pv.x) * vr[1]
                         + bf2f_lo(pv.y) * vr[2] + bf2f_hi(pv.y) * vr[3]
                         + bf2f_lo(pv.z) * vr[4] + bf2f_hi(pv.z) * vr[5]
                         + bf2f_lo(pv.w) * vr[6] + bf2f_hi(pv.w) * vr[7];
                rd = wred64(rd);
                float q = MARG / rd;
                if (!isfinite(q)) q = MARG;
                if (lane == 0) u_sU[w * 16 + r] = q;
            }
        }
        // ---- 6. poll chain V -> v_sV ----
        {
            const unsigned* crd = colp + ((((2 + bank) * 64 + b) * 8) << 9);    // chain V
            unsigned got0[8], got1[8];
            for (;;) {
                bool o = true;
#pragma unroll
                for (int p = 0; p < 8; p++) {
                    got0[p] = __hip_atomic_load(&crd[(p << 9) + col0], __ATOMIC_RELAXED,
                                                __HIP_MEMORY_SCOPE_AGENT);
                    got1[p] = __hip_atomic_load(&crd[(p << 9) + col1], __ATOMIC_RELAXED,
                                                __HIP_MEMORY_SCOPE_AGENT);
                }
#pragma unroll
                for (int p = 0; p < 8; p++)
                    o = o && ((got0[p] & 0xFFFFu) == tag) && ((got1[p] & 0xFFFFu) == tag);
                if (o) break;
                __builtin_amdgcn_s_sleep(1);
            }
            float r0 = 0.f, r1 = 0.f;
#pragma unroll
            for (int p = 0; p < 8; p++) {
                r0 += __uint_as_float(got0[p] & 0xFFFF0000u);
                r1 += __uint_as_float(got1[p] & 0xFFFF0000u);
            }
            float q0 = MARG / r0; if (!isfinite(q0)) q0 = MARG;
            float q1 = MARG / r1; if (!isfinite(q1)) q1 = MARG;
            v_sV[col0] = q0;
            v_sV[col1] = q1;
        }
        __syncthreads();   // D: v_sV (and u_sU) ready for next double-step
    }

    // ---- final contraction: u_100 (u_sU) x v_100 (v_sV) ; C = -0.1*log(P0) ----
    float vr[8];
#pragma unroll
    for (int k = 0; k < 8; ++k) vr[k] = v_sV[lane * 8 + k];
    float acc = 0.f;
#pragma unroll
    for (int r = 0; r < 16; ++r) {
        float u_r = u_sU[w * 16 + r];
        uint4 pv = pw[r];
        float f[8];
        f[0] = bf2f_lo(pv.x); f[1] = bf2f_hi(pv.x);
        f[2] = bf2f_lo(pv.y); f[3] = bf2f_hi(pv.y);
        f[4] = bf2f_lo(pv.z); f[5] = bf2f_hi(pv.z);
        f[6] = bf2f_lo(pv.w); f[7] = bf2f_hi(pv.w);
#pragma unroll
        for (int k = 0; k < 8; ++k) {
            float p = f[k];
            acc += u_r * p * vr[k] * (-0.1f) * logf(p);
        }
    }
    acc = wred64(acc);
    if (lane == 0) bs[w] = acc;
    __syncthreads();
    if (t == 0) {
        float c = (bs[0] + bs[1] + bs[2] + bs[3]) * (1.0f / 64.0f);   // /B
        atomicAdd(&outf[1], c);
        atomicAdd(&outf[2], c);
    }
}

extern "C" void kernel_launch(void* const* d_in, const int* in_sizes, int n_in,
                              void* d_out, int out_size, void* d_ws, size_t ws_size,
                              hipStream_t stream) {
    const void* sg = d_in[0];
    const void* qg = d_in[1];
    const void* an = d_in[2];
    const void* bn = d_in[3];
    char* ws = (char*)d_ws;
    float* outf = (float*)d_out;                     // output dtype: float32 x3

    float* simg     = (float*)(ws + O_SIMG);
    float* rnan     = (float*)(ws + O_RNAN);
    float* rnbn     = (float*)(ws + O_RNBN);
    unsigned* colp  = (unsigned*)(ws + O_COLP);      // 2 chains x 2 tagged banks
    unsigned short* p0 = (unsigned short*)(ws + O_P0);

    k_rnormAB<<<16384, 256, 0, stream>>>(an, bn, rnan, rnbn);
    k_simg<<<16, 256, 0, stream>>>(sg, qg, simg);
    k_gloss<<<1, 256, 0, stream>>>(simg, outf);
    k_build<<<dim3(16, 64), 256, 0, stream>>>(an, bn, rnan, rnbn, p0);
    k_persist<<<512, 256, 0, stream>>>(p0, colp, outf);
}

// Round 12
// 754.957 us; speedup vs baseline: 4.9864x; 1.0280x over previous
//
#include <hip/hip_runtime.h>
#include <cstdint>
#include <cmath>

// Problem constants (fixed by reference):
//   B=64 examples, D=128 dim, NP=512 nodes/tokens per example, 100 Jacobi Sinkhorn iters.
#define NB_EX 64
#define DIMD 128
#define NP 512
constexpr float MARG = 1.0f / 512.0f;   // a = b = 1/n

// ---------- helpers ----------
__device__ __forceinline__ float bf2f_lo(unsigned w) { return __uint_as_float(w << 16); }
__device__ __forceinline__ float bf2f_hi(unsigned w) { return __uint_as_float(w & 0xFFFF0000u); }
__device__ __forceinline__ unsigned short f2bf(float f) {
    unsigned u = __float_as_uint(f);
    u += 0x7FFFu + ((u >> 16) & 1u);      // RTNE
    return (unsigned short)(u >> 16);
}
__device__ __forceinline__ float wred64(float v) {
#pragma unroll
    for (int m = 1; m < 64; m <<= 1) v += __shfl_xor(v, m, 64);
    return v;
}

// sc0 global load: bypasses L1, served by the XCD's shared L2 (the exchange fast path).
// Load + waitcnt live in ONE asm block so the output is valid when the block retires.
__device__ __forceinline__ unsigned l2_sc0_load(const unsigned* p) {
    unsigned v;
    asm volatile("global_load_dword %0, %1, off sc0\n\ts_waitcnt vmcnt(0)"
                 : "=v"(v) : "v"(p) : "memory");
    return v;
}

// Per-block dtype self-detection (bf16-pair low halfword exponent clusters in [110,130];
// fp32 low mantissa bits hit ~8%). 256-thread blocks only. Costs one syncthreads.
__device__ __forceinline__ int self_detect(const unsigned* probe, int t) {
    __shared__ int sd_cnt[4];
    unsigned w = probe[t];
    unsigned e = (w >> 7) & 0xFFu;
    unsigned long long m = __ballot(e >= 110u && e <= 130u);
    if ((t & 63) == 0) sd_cnt[t >> 6] = __popcll(m);
    __syncthreads();
    int c = sd_cnt[0] + sd_cnt[1] + sd_cnt[2] + sd_cnt[3];
    __syncthreads();
    return c >= 128;
}

// ---------- workspace layout (bytes) ----------
#define O_SIMG   0               // 64*64 f32 (16384)
#define O_RNAN   16384           // 32768 f32 (131072)
#define O_RNBN   147456          // 32768 f32 (131072)
#define O_COLP   278528          // L2 copy: 2 chains x 2 banks x 64ex x 4blk x 512 u32 (2 MB)
#define O_COLPIF 2375680         // IF copy: same shape (2 MB) -> both fit the old 4 MB window
#define O_P0     4472832         // 64*512*512 bf16 (33554432) -> total ~38 MB (proven fit)

// ---------- fused inverse L2 norms for struct_nodes + seq_tokens (65536 rows) ----------
__global__ void k_rnormAB(const void* anr, const void* bnr, float* rnan, float* rnbn) {
    int t = threadIdx.x;
    int flag = self_detect((const unsigned*)anr, t);
    int gr  = blockIdx.x * 4 + (t >> 6);      // global row 0..65535
    int lane = t & 63;
    const void* in = (gr < 32768) ? anr : bnr;
    float* rn      = (gr < 32768) ? rnan : rnbn;
    int row = gr & 32767;
    float f0, f1;
    if (flag) {
        unsigned w = ((const unsigned*)in)[row * 64 + lane];
        f0 = bf2f_lo(w); f1 = bf2f_hi(w);
    } else {
        float2 v = ((const float2*)in)[row * 64 + lane];
        f0 = v.x; f1 = v.y;
    }
    float ss = wred64(f0 * f0 + f1 * f1);
    if (lane == 0) rn[row] = 1.0f / fmaxf(sqrtf(ss), 1e-12f);
}

// ---------- global sim logits (self-detecting, self-normalizing) ----------
__global__ void k_simg(const void* sgr, const void* qgr, float* simg) {
    __shared__ float rls[128];                // [0..63]=1/||s_i||, [64..127]=1/||q_j||
    int t = threadIdx.x;
    int flag = self_detect((const unsigned*)sgr, t);
    int w = t >> 6, lane = t & 63;
    for (int rr = 0; rr < 32; rr++) {         // each wave: 32 of 128 rows
        int ri = w * 32 + rr;
        const void* base = (ri < 64) ? sgr : qgr;
        int row = ri & 63;
        float f0, f1;
        if (flag) {
            unsigned wd = ((const unsigned*)base)[row * 64 + lane];
            f0 = bf2f_lo(wd); f1 = bf2f_hi(wd);
        } else {
            float2 v = ((const float2*)base)[row * 64 + lane];
            f0 = v.x; f1 = v.y;
        }
        float ss = wred64(f0 * f0 + f1 * f1);
        if (lane == 0) rls[ri] = 1.0f / fmaxf(sqrtf(ss), 1e-12f);
    }
    __syncthreads();
    int g = blockIdx.x * 256 + t;             // 4096 = 64*64
    int i = g >> 6, j = g & 63;
    float dot = 0.f;
    if (flag) {
        const unsigned* a = (const unsigned*)sgr + i * 64;
        const unsigned* b = (const unsigned*)qgr + j * 64;
        for (int k = 0; k < 64; k++) {
            unsigned wa = a[k], wb = b[k];
            dot += bf2f_lo(wa) * bf2f_lo(wb);
            dot += bf2f_hi(wa) * bf2f_hi(wb);
        }
    } else {
        const float4* a = (const float4*)sgr + i * 32;
        const float4* b = (const float4*)qgr + j * 32;
        for (int k = 0; k < 32; k++) {
            float4 x = a[k], y = b[k];
            dot += x.x * y.x + x.y * y.y + x.z * y.z + x.w * y.w;
        }
    }
    simg[g] = dot * rls[i] * rls[64 + j] * 10.0f;   // /TEMP = *10
}

// ---------- global NT-Xent; initializes all 3 outputs (stores, not adds) ----------
__global__ void k_gloss(const float* __restrict__ simg, float* outf) {
    __shared__ float red[64];
    int i = threadIdx.x;
    if (i < 64) {
        float m = -1e30f;
        for (int j = 0; j < 64; j++) m = fmaxf(m, simg[i * 64 + j]);
        float se = 0.f;
        for (int j = 0; j < 64; j++) se += expf(simg[i * 64 + j] - m);
        float rl = simg[i * 64 + i] - (m + logf(se));
        float m2 = -1e30f;
        for (int j = 0; j < 64; j++) m2 = fmaxf(m2, simg[j * 64 + i]);
        float se2 = 0.f;
        for (int j = 0; j < 64; j++) se2 += expf(simg[j * 64 + i] - m2);
        float cl = simg[i * 64 + i] - (m2 + logf(se2));
        red[i] = rl + cl;
    }
    __syncthreads();
    if (i == 0) {
        float s = 0.f;
        for (int k = 0; k < 64; k++) s += red[k];
        float g = -s / 128.0f;
        outf[0] = g;          // global loss
        outf[1] = 0.0f;       // local loss accumulated by k_persist
        outf[2] = g;          // total = g + local (added by k_persist)
    }
}

// ---------- build P0 = exp(10*sim) bf16, per-example 512x512, 128x128 tiles ----------
__global__ void k_build(const void* anr, const void* bnr, const float* rnan, const float* rnbn,
                        unsigned short* p0) {
    int t  = threadIdx.x;
    int flag = self_detect((const unsigned*)anr, t);
    int b   = blockIdx.y;
    int r0t = (blockIdx.x >> 2) * 128;
    int c0t = (blockIdx.x & 3) * 128;
    __shared__ float As[128][33];
    __shared__ float Bs[128][33];
    int tr = t >> 4, tc = t & 15;
    float acc[8][8];
#pragma unroll
    for (int i = 0; i < 8; i++)
#pragma unroll
        for (int j = 0; j < 8; j++) acc[i][j] = 0.f;

    for (int kc = 0; kc < 4; kc++) {            // K chunks of 32
        for (int ii = 0; ii < 4; ii++) {
            int idx = t + 256 * ii;             // 0..1023 -> 128 rows x 8 float4
            int r = idx >> 3, c4 = idx & 7;
            {   // A chunk (struct_nodes)
                int grow = b * NP + r0t + r;
                float sc = rnan[grow];
                float f0, f1, f2, f3;
                if (flag) {
                    const unsigned* src = (const unsigned*)anr + ((grow * DIMD + kc * 32 + c4 * 4) >> 1);
                    unsigned w0 = src[0], w1 = src[1];
                    f0 = bf2f_lo(w0); f1 = bf2f_hi(w0); f2 = bf2f_lo(w1); f3 = bf2f_hi(w1);
                } else {
                    float4 v = *((const float4*)((const float*)anr + grow * DIMD + kc * 32 + c4 * 4));
                    f0 = v.x; f1 = v.y; f2 = v.z; f3 = v.w;
                }
                As[r][c4 * 4 + 0] = f0 * sc; As[r][c4 * 4 + 1] = f1 * sc;
                As[r][c4 * 4 + 2] = f2 * sc; As[r][c4 * 4 + 3] = f3 * sc;
            }
            {   // B chunk (seq_tokens)
                int grow = b * NP + c0t + r;
                float sc = rnbn[grow];
                float f0, f1, f2, f3;
                if (flag) {
                    const unsigned* src = (const unsigned*)bnr + ((grow * DIMD + kc * 32 + c4 * 4) >> 1);
                    unsigned w0 = src[0], w1 = src[1];
                    f0 = bf2f_lo(w0); f1 = bf2f_hi(w0); f2 = bf2f_lo(w1); f3 = bf2f_hi(w1);
                } else {
                    float4 v = *((const float4*)((const float*)bnr + grow * DIMD + kc * 32 + c4 * 4));
                    f0 = v.x; f1 = v.y; f2 = v.z; f3 = v.w;
                }
                Bs[r][c4 * 4 + 0] = f0 * sc; Bs[r][c4 * 4 + 1] = f1 * sc;
                Bs[r][c4 * 4 + 2] = f2 * sc; Bs[r][c4 * 4 + 3] = f3 * sc;
            }
        }
        __syncthreads();
        for (int kk = 0; kk < 32; kk++) {
            float av[8], bv[8];
#pragma unroll
            for (int i = 0; i < 8; i++) av[i] = As[tr * 8 + i][kk];
#pragma unroll
            for (int j = 0; j < 8; j++) bv[j] = Bs[tc * 8 + j][kk];
#pragma unroll
            for (int i = 0; i < 8; i++)
#pragma unroll
                for (int j = 0; j < 8; j++) acc[i][j] += av[i] * bv[j];
        }
        __syncthreads();
    }
#pragma unroll
    for (int i = 0; i < 8; i++) {
        int grow = b * NP + r0t + tr * 8 + i;
        unsigned short h[8];
#pragma unroll
        for (int j = 0; j < 8; j++) h[j] = f2bf(expf(acc[i][j] * 10.0f));   // exp(sim/REG)
        uint4 pk;
        pk.x = (unsigned)h[0] | ((unsigned)h[1] << 16);
        pk.y = (unsigned)h[2] | ((unsigned)h[3] << 16);
        pk.z = (unsigned)h[4] | ((unsigned)h[5] << 16);
        pk.w = (unsigned)h[6] | ((unsigned)h[7] << 16);
        *((uint4*)(p0 + ((size_t)grow * NP + c0t + tc * 8))) = pk;
    }
}

// ---------- exchange primitives ----------
// Dual-write: plain store -> lands in this XCD's L2 (fast path for same-XCD partners);
// agent-scope relaxed atomic -> Infinity Cache (the proven, placement-independent path).
__device__ __forceinline__ void store_dual(unsigned* l2p, unsigned* ifp, unsigned v) {
    *l2p = v;
    __hip_atomic_store(ifp, v, __ATOMIC_RELAXED, __HIP_MEMORY_SCOPE_AGENT);
}
// Poll 4 partner slots for 2 columns. Rounds 0..3: sc0/L2 fast path; thereafter: IF path.
// Tag-in-word => no tearing, any-path/any-staleness safe (replays recompute identical bits).
__device__ __forceinline__ void poll_sums(const unsigned* crdL2, const unsigned* crdIF,
                                          unsigned tag, int col0, int col1,
                                          float& r0, float& r1) {
    unsigned got[8];
    unsigned need = 0xFFu;
    int round = 0;
    while (need) {
#pragma unroll
        for (int p = 0; p < 4; ++p) {
            unsigned m0 = 1u << p, m1 = 1u << (p + 4);
            if (need & m0) {
                unsigned g = (round < 4)
                    ? l2_sc0_load(crdL2 + (p << 9) + col0)
                    : __hip_atomic_load(crdIF + (p << 9) + col0, __ATOMIC_RELAXED,
                                        __HIP_MEMORY_SCOPE_AGENT);
                if ((g & 0xFFFFu) == tag) { got[p] = g; need &= ~m0; }
            }
            if (need & m1) {
                unsigned g = (round < 4)
                    ? l2_sc0_load(crdL2 + (p << 9) + col1)
                    : __hip_atomic_load(crdIF + (p << 9) + col1, __ATOMIC_RELAXED,
                                        __HIP_MEMORY_SCOPE_AGENT);
                if ((g & 0xFFFFu) == tag) { got[p + 4] = g; need &= ~m1; }
            }
        }
        if (need) __builtin_amdgcn_s_sleep(1);
        ++round;
    }
    r0 = 0.f; r1 = 0.f;
#pragma unroll
    for (int p = 0; p < 4; ++p) {
        r0 += __uint_as_float(got[p] & 0xFFFF0000u);
        r1 += __uint_as_float(got[p + 4] & 0xFFFF0000u);
    }
}

// ---------- persistent Sinkhorn: dual-chain, 4 blocks/example, XCD-local fast exchange ----------
// R11 evidence: exchange stall 3.9 us/exchange regardless of schedule; causes: (a) agent
// atomics always route to the IF, (b) max-of-8 rendezvous skew amplified by 2-blocks/CU
// issue competition. Fixes: (1) dual-copy exchange — plain store to L2 + sc0 poll (partners
// share blk%8 -> same XCD -> ~220cyc) with agent-IF copy as the always-correct fallback;
// (2) 4 blocks/example x 128 rows, grid 256 ~ 1 block/CU (launch_bounds(256,1) -> 512-VGPR
// budget; pw[32]=128 payload + ~70 working fits, spill-impossible), fewer partners + no
// co-resident jitter; (3) stacked 8-row butterfly reduction (same per-row shuffle sequence
// = bit-identical, 8-way ILP for the 1-wave/SIMD regime).
// Schedule per double-step (R11's, proven): colU;syncA; storeU+rowV; colV;syncB; pollU;syncC;
// storeV+rowU; pollV;syncD. Mod-2 banks per chain (reuse proof as R10/R11). Tags 1..50;
// 0xAA-poisoned stale ws (0xAAAA) never matches a tag.
__global__ __launch_bounds__(256, 1) void k_persist(const unsigned short* __restrict__ p0,
                                                    unsigned* __restrict__ colpL2,
                                                    unsigned* __restrict__ colpIF,
                                                    float* __restrict__ outf) {
    int blk = blockIdx.x;
    int rb  = blk >> 6;         // 0..3 (partners differ by 64 in blk -> same blk%8 -> same XCD)
    int b   = blk & 63;         // example
    int rowbase = rb * 128;
    int t = threadIdx.x, w = t >> 6, lane = t & 63;

    __shared__ float credU[4][512];
    __shared__ float credV[4][512];
    __shared__ float v_sU[512];
    __shared__ float v_sV[512];
    __shared__ float u_sU[128];
    __shared__ float u_sV[128];
    __shared__ float bs[4];

    // this lane's static P0 slice: 32 rows x 8 cols packed bf16 = 128 VGPRs
    uint4 pw[32];
#pragma unroll
    for (int r = 0; r < 32; r++) {
        int row = rowbase + w * 32 + r;
        pw[r] = ((const uint4*)(p0 + (((size_t)(b << 9) + row) << 9)))[lane];
    }
    int col0 = t, col1 = t + 256;
    if (t < 128) u_sU[t] = MARG;                   // u_0 = a
    v_sV[col0] = MARG; v_sV[col1] = MARG;          // v_0 = b
    __syncthreads();

#pragma unroll 1
    for (int s = 0; s < 50; ++s) {
        unsigned tag = (unsigned)(s + 1);
        int bank = s & 1;
        // ---- 1. col pass chain U ----
        {
            float ca[8];
#pragma unroll
            for (int k = 0; k < 8; ++k) ca[k] = 0.f;
#pragma unroll
            for (int r = 0; r < 32; ++r) {
                float u_r = u_sU[w * 32 + r];
                uint4 pv = pw[r];
                ca[0] += bf2f_lo(pv.x) * u_r; ca[1] += bf2f_hi(pv.x) * u_r;
                ca[2] += bf2f_lo(pv.y) * u_r; ca[3] += bf2f_hi(pv.y) * u_r;
                ca[4] += bf2f_lo(pv.z) * u_r; ca[5] += bf2f_hi(pv.z) * u_r;
                ca[6] += bf2f_lo(pv.w) * u_r; ca[7] += bf2f_hi(pv.w) * u_r;
            }
#pragma unroll
            for (int k = 0; k < 8; ++k) credU[w][lane * 8 + k] = ca[k];
        }
        __syncthreads();   // A
        // ---- 2. store U (dual, fire-and-forget), then rowpass V (local) ----
        {
            int slot = ((bank * 64 + b) * 4 + rb) << 9;                  // chain U
            float s0 = credU[0][col0] + credU[1][col0] + credU[2][col0] + credU[3][col0];
            float s1 = credU[0][col1] + credU[1][col1] + credU[2][col1] + credU[3][col1];
            store_dual(colpL2 + slot + col0, colpIF + slot + col0,
                       ((unsigned)f2bf(s0) << 16) | tag);
            store_dual(colpL2 + slot + col1, colpIF + slot + col1,
                       ((unsigned)f2bf(s1) << 16) | tag);
        }
        {   // rowpass V: u'_{2s+1} = a/(P0 v_2s) -> u_sV (wave-local)
            float vr[8];
#pragma unroll
            for (int k = 0; k < 8; ++k) vr[k] = v_sV[lane * 8 + k];
#pragma unroll
            for (int g = 0; g < 4; ++g) {
                float rp[8];
#pragma unroll
                for (int j = 0; j < 8; ++j) {
                    uint4 pv = pw[g * 8 + j];
                    rp[j] = bf2f_lo(pv.x) * vr[0] + bf2f_hi(pv.x) * vr[1]
                          + bf2f_lo(pv.y) * vr[2] + bf2f_hi(pv.y) * vr[3]
                          + bf2f_lo(pv.z) * vr[4] + bf2f_hi(pv.z) * vr[5]
                          + bf2f_lo(pv.w) * vr[6] + bf2f_hi(pv.w) * vr[7];
                }
#pragma unroll
                for (int m = 1; m < 64; m <<= 1)
#pragma unroll
                    for (int j = 0; j < 8; ++j) rp[j] += __shfl_xor(rp[j], m, 64);
                float sel = rp[0];
#pragma unroll
                for (int j = 1; j < 8; ++j) if (lane == j) sel = rp[j];
                if (lane < 8) {
                    float q = MARG / sel;
                    if (!isfinite(q)) q = MARG;
                    u_sV[w * 32 + g * 8 + lane] = q;
                }
            }
        }
        // ---- 3. col pass chain V ----
        {
            float ca[8];
#pragma unroll
            for (int k = 0; k < 8; ++k) ca[k] = 0.f;
#pragma unroll
            for (int r = 0; r < 32; ++r) {
                float u_r = u_sV[w * 32 + r];      // same-wave RAW, lgkmcnt only
                uint4 pv = pw[r];
                ca[0] += bf2f_lo(pv.x) * u_r; ca[1] += bf2f_hi(pv.x) * u_r;
                ca[2] += bf2f_lo(pv.y) * u_r; ca[3] += bf2f_hi(pv.y) * u_r;
                ca[4] += bf2f_lo(pv.z) * u_r; ca[5] += bf2f_hi(pv.z) * u_r;
                ca[6] += bf2f_lo(pv.w) * u_r; ca[7] += bf2f_hi(pv.w) * u_r;
            }
#pragma unroll
            for (int k = 0; k < 8; ++k) credV[w][lane * 8 + k] = ca[k];
        }
        __syncthreads();   // B (store U long since drained)
        // ---- 4. poll chain U -> v_sU ----
        {
            int base = ((bank * 64 + b) * 4) << 9;                       // chain U
            float r0, r1;
            poll_sums(colpL2 + base, colpIF + base, tag, col0, col1, r0, r1);
            float q0 = MARG / r0; if (!isfinite(q0)) q0 = MARG;
            float q1 = MARG / r1; if (!isfinite(q1)) q1 = MARG;
            v_sU[col0] = q0;
            v_sU[col1] = q1;
        }
        __syncthreads();   // C
        // ---- 5. store V (dual), then rowpass U (local) ----
        {
            int slot = (((2 + bank) * 64 + b) * 4 + rb) << 9;            // chain V
            float s0 = credV[0][col0] + credV[1][col0] + credV[2][col0] + credV[3][col0];
            float s1 = credV[0][col1] + credV[1][col1] + credV[2][col1] + credV[3][col1];
            store_dual(colpL2 + slot + col0, colpIF + slot + col0,
                       ((unsigned)f2bf(s0) << 16) | tag);
            store_dual(colpL2 + slot + col1, colpIF + slot + col1,
                       ((unsigned)f2bf(s1) << 16) | tag);
        }
        {   // rowpass U: u_{2s+2} = a/(P0 v'_{2s+1}) -> u_sU (wave-local)
            float vr[8];
#pragma unroll
            for (int k = 0; k < 8; ++k) vr[k] = v_sU[lane * 8 + k];
#pragma unroll
            for (int g = 0; g < 4; ++g) {
                float rp[8];
#pragma unroll
                for (int j = 0; j < 8; ++j) {
                    uint4 pv = pw[g * 8 + j];
                    rp[j] = bf2f_lo(pv.x) * vr[0] + bf2f_hi(pv.x) * vr[1]
                          + bf2f_lo(pv.y) * vr[2] + bf2f_hi(pv.y) * vr[3]
                          + bf2f_lo(pv.z) * vr[4] + bf2f_hi(pv.z) * vr[5]
                          + bf2f_lo(pv.w) * vr[6] + bf2f_hi(pv.w) * vr[7];
                }
#pragma unroll
                for (int m = 1; m < 64; m <<= 1)
#pragma unroll
                    for (int j = 0; j < 8; ++j) rp[j] += __shfl_xor(rp[j], m, 64);
                float sel = rp[0];
#pragma unroll
                for (int j = 1; j < 8; ++j) if (lane == j) sel = rp[j];
                if (lane < 8) {
                    float q = MARG / sel;
                    if (!isfinite(q)) q = MARG;
                    u_sU[w * 32 + g * 8 + lane] = q;
                }
            }
        }
        // ---- 6. poll chain V -> v_sV ----
        {
            int base = (((2 + bank) * 64 + b) * 4) << 9;                 // chain V
            float r0, r1;
            poll_sums(colpL2 + base, colpIF + base, tag, col0, col1, r0, r1);
            float q0 = MARG / r0; if (!isfinite(q0)) q0 = MARG;
            float q1 = MARG / r1; if (!isfinite(q1)) q1 = MARG;
            v_sV[col0] = q0;
            v_sV[col1] = q1;
        }
        __syncthreads();   // D
    }

    // ---- final contraction: u_100 (u_sU) x v_100 (v_sV) ; C = -0.1*log(P0) ----
    float vr[8];
#pragma unroll
    for (int k = 0; k < 8; ++k) vr[k] = v_sV[lane * 8 + k];
    float acc = 0.f;
#pragma unroll
    for (int r = 0; r < 32; ++r) {
        float u_r = u_sU[w * 32 + r];
        uint4 pv = pw[r];
        float f[8];
        f[0] = bf2f_lo(pv.x); f[1] = bf2f_hi(pv.x);
        f[2] = bf2f_lo(pv.y); f[3] = bf2f_hi(pv.y);
        f[4] = bf2f_lo(pv.z); f[5] = bf2f_hi(pv.z);
        f[6] = bf2f_lo(pv.w); f[7] = bf2f_hi(pv.w);
#pragma unroll
        for (int k = 0; k < 8; ++k) {
            float p = f[k];
            acc += u_r * p * vr[k] * (-0.1f) * logf(p);
        }
    }
    acc = wred64(acc);
    if (lane == 0) bs[w] = acc;
    __syncthreads();
    if (t == 0) {
        float c = (bs[0] + bs[1] + bs[2] + bs[3]) * (1.0f / 64.0f);   // /B
        atomicAdd(&outf[1], c);
        atomicAdd(&outf[2], c);
    }
}

extern "C" void kernel_launch(void* const* d_in, const int* in_sizes, int n_in,
                              void* d_out, int out_size, void* d_ws, size_t ws_size,
                              hipStream_t stream) {
    const void* sg = d_in[0];
    const void* qg = d_in[1];
    const void* an = d_in[2];
    const void* bn = d_in[3];
    char* ws = (char*)d_ws;
    float* outf = (float*)d_out;                     // output dtype: float32 x3

    float* simg      = (float*)(ws + O_SIMG);
    float* rnan      = (float*)(ws + O_RNAN);
    float* rnbn      = (float*)(ws + O_RNBN);
    unsigned* colpL2 = (unsigned*)(ws + O_COLP);     // L2-resident tagged copy
    unsigned* colpIF = (unsigned*)(ws + O_COLPIF);   // IF-resident tagged copy (fallback)
    unsigned short* p0 = (unsigned short*)(ws + O_P0);

    k_rnormAB<<<16384, 256, 0, stream>>>(an, bn, rnan, rnbn);
    k_simg<<<16, 256, 0, stream>>>(sg, qg, simg);
    k_gloss<<<1, 256, 0, stream>>>(simg, outf);
    k_build<<<dim3(16, 64), 256, 0, stream>>>(an, bn, rnan, rnbn, p0);
    k_persist<<<256, 256, 0, stream>>>(p0, colpL2, colpIF, outf);
}